// Round 11
// baseline (441.955 us; speedup 1.0000x reference)
//
#include <hip/hip_runtime.h>
#include <hip/hip_fp16.h>

#define N_NODES 100000
#define N_EDGES 3200000
#define N_GRAPHS 64
#define IN_DIM 128
#define HIDDEN 64
#define LATENT 16

#define NC 256          // coarse dst/src buckets (512 nodes each), node>>9
#define CSHIFT 9
#define NBC_USED 196    // ceil(100000/512)
#define SC_BLOCKS 128
#define NKEYS 4096      // sub(8) x chunk(8) x owner(8) x row(8)
#define NBLK_AGG 1563   // 64-node aggregate blocks
#define NSEG (NBC_USED * 8 * 64)  // 100352 segment offsets

// ---------------- tiny zero kernel ----------------
__global__ __launch_bounds__(256) void zero_k(int4* __restrict__ p, int n4) {
  int i = blockIdx.x * 256 + threadIdx.x;
  if (i < n4) p[i] = make_int4(0, 0, 0, 0);
}

// ---------------- pass A: coarse histograms (256 buckets); dump per-block counts ----
__global__ __launch_bounds__(256) void hist_c_k(const int4* __restrict__ src4,
                                                const int4* __restrict__ dst4,
                                                int* __restrict__ bc_src,
                                                int* __restrict__ bc_dst,
                                                int* __restrict__ tbl_src,
                                                int* __restrict__ tbl_dst) {
  __shared__ int hs[NC], hd[NC];
  int t = threadIdx.x;
  if (t < NC) { hs[t] = 0; hd[t] = 0; }
  __syncthreads();
  const int Q = N_EDGES / 4;
  const int QPB = Q / SC_BLOCKS;
  int q0 = blockIdx.x * QPB, q1 = q0 + QPB;
  for (int i = q0 + t; i < q1; i += 256) {
    int4 s = src4[i], d = dst4[i];
    atomicAdd(&hs[s.x >> CSHIFT], 1); atomicAdd(&hs[s.y >> CSHIFT], 1);
    atomicAdd(&hs[s.z >> CSHIFT], 1); atomicAdd(&hs[s.w >> CSHIFT], 1);
    atomicAdd(&hd[d.x >> CSHIFT], 1); atomicAdd(&hd[d.y >> CSHIFT], 1);
    atomicAdd(&hd[d.z >> CSHIFT], 1); atomicAdd(&hd[d.w >> CSHIFT], 1);
  }
  __syncthreads();
  if (t < NC) {
    int a = hs[t], b = hd[t];
    tbl_src[blockIdx.x * NC + t] = a;
    tbl_dst[blockIdx.x * NC + t] = b;
    if (a) atomicAdd(&bc_src[t], a);
    if (b) atomicAdd(&bc_dst[t], b);
  }
}

// ---------------- pass B: exclusive scan of both 256-entry count arrays ----------------
__global__ __launch_bounds__(256) void scan_c_k(const int* __restrict__ bc_src,
                                                const int* __restrict__ bc_dst,
                                                int* __restrict__ bbase_src,
                                                int* __restrict__ bbase_dst) {
  __shared__ int a[NC], b[NC];
  int t = threadIdx.x;
  int va = bc_src[t], vb = bc_dst[t];
  a[t] = va; b[t] = vb;
  __syncthreads();
  for (int off = 1; off < NC; off <<= 1) {
    int xa = 0, xb = 0;
    if (t >= off) { xa = a[t - off]; xb = b[t - off]; }
    __syncthreads();
    if (t >= off) { a[t] += xa; b[t] += xb; }
    __syncthreads();
  }
  bbase_src[t] = a[t] - va;
  bbase_dst[t] = b[t] - vb;
  if (t == NC - 1) {
    bbase_src[NC] = a[t];
    bbase_dst[NC] = b[t];
  }
}

// ---------------- pass C: coarse scatter (long runs -> low write amplification) ----
__global__ __launch_bounds__(256) void scatter_c_k(const int4* __restrict__ src4,
                                                   const int4* __restrict__ dst4,
                                                   const int* __restrict__ bbase_src,
                                                   const int* __restrict__ bbase_dst,
                                                   const int* __restrict__ tbl_src,
                                                   const int* __restrict__ tbl_dst,
                                                   int* __restrict__ cur_src,
                                                   int* __restrict__ cur_dst,
                                                   int* __restrict__ sortedS,
                                                   int* __restrict__ sortedE) {
  __shared__ int rs[NC], rd[NC];
  int t = threadIdx.x;
  if (t < NC) {
    int a = tbl_src[blockIdx.x * NC + t];
    int b = tbl_dst[blockIdx.x * NC + t];
    rs[t] = a ? (atomicAdd(&cur_src[t], a) + bbase_src[t]) : 0;
    rd[t] = b ? (atomicAdd(&cur_dst[t], b) + bbase_dst[t]) : 0;
  }
  __syncthreads();
  const int Q = N_EDGES / 4;
  const int QPB = Q / SC_BLOCKS;
  int q0 = blockIdx.x * QPB, q1 = q0 + QPB;
  for (int i = q0 + t; i < q1; i += 256) {
    int4 s = src4[i], d = dst4[i];
    int sv[4] = {s.x, s.y, s.z, s.w};
    int dv[4] = {d.x, d.y, d.z, d.w};
#pragma unroll
    for (int k = 0; k < 4; k++) {
      int ps = atomicAdd(&rs[sv[k] >> CSHIFT], 1);
      sortedS[ps] = sv[k];
      int pd = atomicAdd(&rd[dv[k] >> CSHIFT], 1);
      sortedE[pd] = ((dv[k] & 511) << 17) | sv[k];
    }
  }
}

// ---------------- pass D: per-coarse-bucket sort by (sub64, chunk, owner, dstrow) ----
// No LDS edge staging (second sortedE read is L2-hot): 34KB LDS -> 4 blocks/CU.
__global__ __launch_bounds__(256) void fine_sort_k(const int* __restrict__ sortedE,
                                                   const int* __restrict__ bbase_dst,
                                                   int* __restrict__ deg_in,
                                                   int* __restrict__ seg,
                                                   int* __restrict__ eblk) {
  __shared__ int hist[NKEYS];         // 16384 B
  __shared__ int cur[NKEYS];          // 16384 B
  __shared__ int ts[256];
  int bk = blockIdx.x, t = threadIdx.x;
  int node0 = bk << CSHIFT;
  int e0 = bbase_dst[bk], e1 = bbase_dst[bk + 1];
  for (int i = t; i < NKEYS; i += 256) hist[i] = 0;
  __syncthreads();
  // key histogram. key = sub*512 + chunk*64 + owner*8 + row
  for (int j = e0 + t; j < e1; j += 256) {
    int v = sortedE[j];
    int d9 = v >> 17, sr = v & 0x1FFFF;
    int key = ((d9 >> 6) << 9) | ((sr >> 14) << 6) | ((d9 & 7) << 3) | ((d9 >> 3) & 7);
    atomicAdd(&hist[key], 1);
  }
  __syncthreads();
  // exclusive scan over 4096 keys (16/thread + block scan)
  int b16 = 16 * t;
  int s = 0;
#pragma unroll
  for (int k = 0; k < 16; k++) s += hist[b16 + k];
  ts[t] = s;
  __syncthreads();
  for (int off = 1; off < 256; off <<= 1) {
    int x = 0;
    if (t >= off) x = ts[t - off];
    __syncthreads();
    if (t >= off) ts[t] += x;
    __syncthreads();
  }
  int run = ts[t] - s;
#pragma unroll
  for (int k = 0; k < 16; k++) { cur[b16 + k] = run; run += hist[b16 + k]; }
  __syncthreads();
  // deg_in (2 nodes per thread)
#pragma unroll
  for (int k = 0; k < 2; k++) {
    int l = t + k * 256;
    int n = node0 + l;
    if (n < N_NODES) {
      int sub = l >> 6, o = l & 7, row = (l >> 3) & 7;
      int base = (sub << 9) | (o << 3) | row;
      int dg = 0;
#pragma unroll
      for (int c = 0; c < 8; c++) dg += hist[base + (c << 6)];
      deg_in[n] = dg;
    }
  }
  // seg offsets: one per (sub, chunk, owner)
  for (int i = t; i < 512; i += 256) {
    int sub = i >> 6, c = (i >> 3) & 7, o = i & 7;
    seg[(bk * 8 + sub) * 64 + c * 8 + o] = e0 + cur[(sub << 9) | (c << 6) | (o << 3)];
  }
  if (bk == NBC_USED - 1 && t == 0) seg[NSEG] = N_EDGES;  // sentinel
  __syncthreads();
  // scatter into eblk (re-read sortedE, L2-hot), repacked as (d6<<17)|src
  for (int j = e0 + t; j < e1; j += 256) {
    int v = sortedE[j];
    int d9 = v >> 17, sr = v & 0x1FFFF;
    int key = ((d9 >> 6) << 9) | ((sr >> 14) << 6) | ((d9 & 7) << 3) | ((d9 >> 3) & 7);
    int pos = e0 + atomicAdd(&cur[key], 1);
    eblk[pos] = ((d9 & 63) << 17) | sr;
  }
}

// ---------------- deg_out: per coarse src-bucket LDS hist over sortedS ----------------
__global__ __launch_bounds__(256) void degout_c_k(const int* __restrict__ sortedS,
                                                  const int* __restrict__ bbase_src,
                                                  int* __restrict__ deg_out) {
  __shared__ int h[512];
  int bk = blockIdx.x, t = threadIdx.x;
  h[t] = 0; h[t + 256] = 0;
  __syncthreads();
  int s0 = bbase_src[bk], s1 = bbase_src[bk + 1];
  for (int j = s0 + t; j < s1; j += 256) atomicAdd(&h[sortedS[j] & 511], 1);
  __syncthreads();
#pragma unroll
  for (int k = 0; k < 2; k++) {
    int l = 2 * t + k;
    int n = (bk << CSHIFT) + l;
    if (n < N_NODES) deg_out[n] = h[l];
  }
}

// ---------------- register-tiled GEMM: out[n][c] = (X@W)[n][c] * rsqrt(max(deg,1)) ----
template <int IN, typename IT, typename OT>
__global__ __launch_bounds__(256) void gemm_tile_k(const IT* __restrict__ X,
                                                   const float* __restrict__ W,
                                                   const int* __restrict__ deg,
                                                   OT* __restrict__ out) {
  __shared__ float xs[64][IN + 4];
  __shared__ float ws[IN][HIDDEN];
  int t = threadIdx.x;
  int row0_blk = blockIdx.x * 64;

  for (int i = t; i < IN * HIDDEN / 4; i += 256)
    ((float4*)ws)[i] = ((const float4*)W)[i];
  for (int i = t; i < 64 * (IN / 4); i += 256) {
    int r = i / (IN / 4), c4 = i % (IN / 4);
    int row = row0_blk + r;
    float4 v = make_float4(0.f, 0.f, 0.f, 0.f);
    if (row < N_NODES) {
      if constexpr (sizeof(IT) == 4) {
        v = *(const float4*)&X[(size_t)row * IN + c4 * 4];
      } else {
        union { short4 s; __half2 h2[2]; } u;
        u.s = *(const short4*)&X[(size_t)row * IN + c4 * 4];
        float2 f0 = __half22float2(u.h2[0]);
        float2 f1 = __half22float2(u.h2[1]);
        v = make_float4(f0.x, f0.y, f1.x, f1.y);
      }
    }
    *(float4*)&xs[r][c4 * 4] = v;
  }
  __syncthreads();

  int w = t >> 6, lane = t & 63;
  int rg = lane >> 4, cg = lane & 15;
  int r0 = w * 16 + rg * 4;
  int c0 = cg * 4;

  float acc[4][4];
#pragma unroll
  for (int i = 0; i < 4; i++)
#pragma unroll
    for (int j = 0; j < 4; j++) acc[i][j] = 0.f;

#pragma unroll 4
  for (int d4 = 0; d4 < IN / 4; d4++) {
    float4 a0 = *(const float4*)&xs[r0 + 0][d4 * 4];
    float4 a1 = *(const float4*)&xs[r0 + 1][d4 * 4];
    float4 a2 = *(const float4*)&xs[r0 + 2][d4 * 4];
    float4 a3 = *(const float4*)&xs[r0 + 3][d4 * 4];
#pragma unroll
    for (int dd = 0; dd < 4; dd++) {
      float4 b = *(const float4*)&ws[d4 * 4 + dd][c0];
      float av0 = (&a0.x)[dd], av1 = (&a1.x)[dd], av2 = (&a2.x)[dd], av3 = (&a3.x)[dd];
      acc[0][0] += av0 * b.x; acc[0][1] += av0 * b.y; acc[0][2] += av0 * b.z; acc[0][3] += av0 * b.w;
      acc[1][0] += av1 * b.x; acc[1][1] += av1 * b.y; acc[1][2] += av1 * b.z; acc[1][3] += av1 * b.w;
      acc[2][0] += av2 * b.x; acc[2][1] += av2 * b.y; acc[2][2] += av2 * b.z; acc[2][3] += av2 * b.w;
      acc[3][0] += av3 * b.x; acc[3][1] += av3 * b.y; acc[3][2] += av3 * b.z; acc[3][3] += av3 * b.w;
    }
  }

#pragma unroll
  for (int i = 0; i < 4; i++) {
    int row = row0_blk + r0 + i;
    if (row >= N_NODES) continue;
    float dg = (float)deg[row];
    if (dg < 1.f) dg = 1.f;
    float sc = rsqrtf(dg);
    if constexpr (sizeof(OT) == 2) {
      __half2 p0 = __floats2half2_rn(acc[i][0] * sc, acc[i][1] * sc);
      __half2 p1 = __floats2half2_rn(acc[i][2] * sc, acc[i][3] * sc);
      union { __half2 h2[2]; float2 f2; } u;
      u.h2[0] = p0; u.h2[1] = p1;
      *(float2*)&out[(size_t)row * HIDDEN + c0] = u.f2;
    } else {
      float4 o = make_float4(acc[i][0] * sc, acc[i][1] * sc, acc[i][2] * sc, acc[i][3] * sc);
      *(float4*)&out[(size_t)row * HIDDEN + c0] = o;
    }
  }
}

// ---------------- aggregate: block=64 dst nodes, chunk-swept, owner-exclusive LDS ----
// FUSE: after aggregation, B=relu(...) kept in LDS (f32), fused gemm2:
// out = (B @ W2) * rsqrt(max(deg_out,1)) written fp16 (no B round-trip).
template <bool FUSE>
__global__ __launch_bounds__(256) void agg_seg_k(const __half* __restrict__ A,
                                                 const int* __restrict__ eblk,
                                                 const int* __restrict__ seg,
                                                 const int* __restrict__ deg_in,
                                                 const float* __restrict__ bias,
                                                 const float* __restrict__ W2,
                                                 const int* __restrict__ deg_out,
                                                 __half* __restrict__ out) {
  __shared__ float acc[64][68];   // 17408 B (stride 68: 16B-aligned float4 rows)
  __shared__ float ws2[64][64];   // 16384 B (only used when FUSE)
  int bk = blockIdx.x, t = threadIdx.x;
  int o = t >> 5, l = t & 31;  // half-wave owner (0..7), lane covers 2 channels
  for (int i = t; i < 64 * 68; i += 256) ((float*)acc)[i] = 0.f;
  if (FUSE) {
    for (int i = t; i < 64 * 64 / 4; i += 256)
      ((float4*)ws2)[i] = ((const float4*)W2)[i];
  }
  __syncthreads();
  int segbase = bk * 64;
  float rx = 0.f, ry = 0.f;
  int cur_d = -1;
#pragma unroll
  for (int c = 0; c < 8; c++) {
    int j0 = seg[segbase + c * 8 + o];
    int j1 = seg[segbase + c * 8 + o + 1];
    int j = j0;
    for (; j + 16 <= j1; j += 16) {
      int vv[16];
#pragma unroll
      for (int k = 0; k < 16; k++) vv[k] = eblk[j + k];
      float2 ff[16];
#pragma unroll
      for (int k = 0; k < 16; k++)
        ff[k] = __half22float2(*(const __half2*)&A[(size_t)(vv[k] & 0x1FFFF) * HIDDEN + 2 * l]);
#pragma unroll
      for (int k = 0; k < 16; k++) {
        int d = vv[k] >> 17;
        if (d != cur_d) {
          if (cur_d >= 0) {
            float2* ap = (float2*)&acc[cur_d][2 * l];
            float2 a0 = *ap; a0.x += rx; a0.y += ry; *ap = a0;
          }
          cur_d = d; rx = 0.f; ry = 0.f;
        }
        rx += ff[k].x; ry += ff[k].y;
      }
    }
    for (; j + 4 <= j1; j += 4) {
      int vv[4];
#pragma unroll
      for (int k = 0; k < 4; k++) vv[k] = eblk[j + k];
      float2 ff[4];
#pragma unroll
      for (int k = 0; k < 4; k++)
        ff[k] = __half22float2(*(const __half2*)&A[(size_t)(vv[k] & 0x1FFFF) * HIDDEN + 2 * l]);
#pragma unroll
      for (int k = 0; k < 4; k++) {
        int d = vv[k] >> 17;
        if (d != cur_d) {
          if (cur_d >= 0) {
            float2* ap = (float2*)&acc[cur_d][2 * l];
            float2 a0 = *ap; a0.x += rx; a0.y += ry; *ap = a0;
          }
          cur_d = d; rx = 0.f; ry = 0.f;
        }
        rx += ff[k].x; ry += ff[k].y;
      }
    }
    for (; j < j1; j++) {
      int v = eblk[j];
      int d = v >> 17;
      if (d != cur_d) {
        if (cur_d >= 0) {
          float2* ap = (float2*)&acc[cur_d][2 * l];
          float2 a0 = *ap; a0.x += rx; a0.y += ry; *ap = a0;
        }
        cur_d = d; rx = 0.f; ry = 0.f;
      }
      float2 f = __half22float2(*(const __half2*)&A[(size_t)(v & 0x1FFFF) * HIDDEN + 2 * l]);
      rx += f.x; ry += f.y;
    }
  }
  if (cur_d >= 0) {
    float2* ap = (float2*)&acc[cur_d][2 * l];
    float2 a0 = *ap; a0.x += rx; a0.y += ry; *ap = a0;
  }
  __syncthreads();

  int node0 = bk << 6;
  if constexpr (!FUSE) {
    // writeout: scale + bias + relu -> fp16
    for (int i = t; i < 64 * 64; i += 256) {
      int r = i >> 6, ch = i & 63;
      int node = node0 + r;
      if (node >= N_NODES) continue;
      float dg = (float)deg_in[node];
      if (dg < 1.f) dg = 1.f;
      float v = acc[r][ch] * rsqrtf(dg) + bias[ch];
      out[(size_t)node * HIDDEN + ch] = __float2half(v > 0.f ? v : 0.f);
    }
  } else {
    // B = relu(scale + bias) in place (f32)
    for (int i = t; i < 64 * 64; i += 256) {
      int r = i >> 6, ch = i & 63;
      float dg = (float)deg_in[node0 + r];  // alloc padded; garbage rows unused
      if (dg < 1.f) dg = 1.f;
      float v = acc[r][ch] * rsqrtf(dg) + bias[ch];
      acc[r][ch] = v > 0.f ? v : 0.f;
    }
    __syncthreads();
    // fused gemm2: out[n][c2] = (sum_c B[n][c] * W2[c][c2]) * rsqrt(deg_out[n])
    int w = t >> 6, lane = t & 63;
    int rg = lane >> 4, cg = lane & 15;
    int r0 = w * 16 + rg * 4;
    int c0 = cg * 4;
    float oacc[4][4];
#pragma unroll
    for (int i = 0; i < 4; i++)
#pragma unroll
      for (int j = 0; j < 4; j++) oacc[i][j] = 0.f;
#pragma unroll 4
    for (int d = 0; d < 64; d++) {
      float4 b = *(const float4*)&ws2[d][c0];
      float a0 = acc[r0 + 0][d], a1 = acc[r0 + 1][d];
      float a2 = acc[r0 + 2][d], a3 = acc[r0 + 3][d];
      oacc[0][0] += a0 * b.x; oacc[0][1] += a0 * b.y; oacc[0][2] += a0 * b.z; oacc[0][3] += a0 * b.w;
      oacc[1][0] += a1 * b.x; oacc[1][1] += a1 * b.y; oacc[1][2] += a1 * b.z; oacc[1][3] += a1 * b.w;
      oacc[2][0] += a2 * b.x; oacc[2][1] += a2 * b.y; oacc[2][2] += a2 * b.z; oacc[2][3] += a2 * b.w;
      oacc[3][0] += a3 * b.x; oacc[3][1] += a3 * b.y; oacc[3][2] += a3 * b.z; oacc[3][3] += a3 * b.w;
    }
#pragma unroll
    for (int i = 0; i < 4; i++) {
      int node = node0 + r0 + i;
      if (node >= N_NODES) continue;
      float dg = (float)deg_out[node];
      if (dg < 1.f) dg = 1.f;
      float sc = rsqrtf(dg);
      __half2 p0 = __floats2half2_rn(oacc[i][0] * sc, oacc[i][1] * sc);
      __half2 p1 = __floats2half2_rn(oacc[i][2] * sc, oacc[i][3] * sc);
      union { __half2 h2[2]; float2 f2; } u;
      u.h2[0] = p0; u.h2[1] = p1;
      *(float2*)&out[(size_t)node * HIDDEN + c0] = u.f2;
    }
  }
}

// ---------------- per-graph mean pool (sorted node_graph, run-accumulate) ----------------
__global__ __launch_bounds__(256) void pool_k(const __half* __restrict__ h,
                                              const int* __restrict__ node_graph,
                                              float* __restrict__ sums,
                                              float* __restrict__ counts) {
  const int NPW = 256;
  int wave = (int)((blockIdx.x * blockDim.x + threadIdx.x) >> 6);
  int lane = threadIdx.x & 63;
  int start = wave * NPW;
  if (start >= N_NODES) return;
  int end = start + NPW; if (end > N_NODES) end = N_NODES;
  int cur = node_graph[start];
  float acc = 0.f, cnt = 0.f;
  for (int n = start; n < end; n++) {
    int g = node_graph[n];
    if (g != cur) {
      atomicAdd(&sums[cur * HIDDEN + lane], acc);
      if (lane == 0) atomicAdd(&counts[cur], cnt);
      cur = g; acc = 0.f; cnt = 0.f;
    }
    acc += __half2float(h[(size_t)n * HIDDEN + lane]);
    cnt += 1.f;
  }
  atomicAdd(&sums[cur * HIDDEN + lane], acc);
  if (lane == 0) atomicAdd(&counts[cur], cnt);
}

// ---------------- final: h_graph = sums/counts; mu/logvar = h_graph @ Wmu/Wlv + b ----------------
__global__ __launch_bounds__(256) void final_k(const float* __restrict__ sums,
                                               const float* __restrict__ counts,
                                               const float* __restrict__ Wmu,
                                               const float* __restrict__ bmu,
                                               const float* __restrict__ Wlv,
                                               const float* __restrict__ blv,
                                               float* __restrict__ out) {
  __shared__ float hg[N_GRAPHS][HIDDEN];
  __shared__ float wmu[HIDDEN][LATENT];
  __shared__ float wlv[HIDDEN][LATENT];
  int t = threadIdx.x;
  for (int i = t; i < N_GRAPHS * HIDDEN; i += 256) {
    int g = i / HIDDEN;
    float c = counts[g];
    if (c < 1.f) c = 1.f;
    hg[g][i % HIDDEN] = sums[i] / c;
  }
  for (int i = t; i < HIDDEN * LATENT; i += 256) {
    wmu[i / LATENT][i % LATENT] = Wmu[i];
    wlv[i / LATENT][i % LATENT] = Wlv[i];
  }
  __syncthreads();
  for (int i = t; i < N_GRAPHS * LATENT; i += 256) {
    int g = i / LATENT, j = i % LATENT;
    float mu = bmu[j], lv = blv[j];
#pragma unroll
    for (int k = 0; k < HIDDEN; k++) {
      float v = hg[g][k];
      mu += v * wmu[k][j];
      lv += v * wlv[k][j];
    }
    out[i] = mu;
    out[N_GRAPHS * LATENT + i] = lv;
  }
}

extern "C" void kernel_launch(void* const* d_in, const int* in_sizes, int n_in,
                              void* d_out, int out_size, void* d_ws, size_t ws_size,
                              hipStream_t stream) {
  const float* x = (const float*)d_in[0];
  // d_in[1] = edge_feat: provably unused for (mu, logvar)
  const int* src = (const int*)d_in[2];
  const int* dst = (const int*)d_in[3];
  const int* node_graph = (const int*)d_in[4];
  const float* W1 = (const float*)d_in[5];
  const float* b1 = (const float*)d_in[6];
  const float* W2 = (const float*)d_in[7];
  const float* b2 = (const float*)d_in[8];
  // d_in[9] = We, d_in[10] = be: unused
  const float* Wmu = (const float*)d_in[11];
  const float* bmu = (const float*)d_in[12];
  const float* Wlv = (const float*)d_in[13];
  const float* blv = (const float*)d_in[14];
  float* out = (float*)d_out;

  char* ws = (char*)d_ws;
  // zeroed control block [0, 20992)
  int* bc_src   = (int*)(ws + 0);        // 1024
  int* bc_dst   = (int*)(ws + 1024);     // 1024
  int* cur_src  = (int*)(ws + 2048);     // 1024
  int* cur_dst  = (int*)(ws + 3072);     // 1024
  float* cnts   = (float*)(ws + 4096);   // 512
  float* sums   = (float*)(ws + 4608);   // 16384 -> 20992
  // non-zeroed control
  int* bbase_src = (int*)(ws + 21504);   // 1028 (pad)
  int* bbase_dst = (int*)(ws + 22784);   // 1028 (pad)
  int* tbl_src   = (int*)(ws + 24576);   // 131072
  int* tbl_dst   = (int*)(ws + 155648);  // 131072 -> 286720
  // big arrays
  int* deg_out = (int*)(ws + 286720);    // 400128 -> 686848
  int* deg_in  = (int*)(ws + 686848);    // 400128 -> 1086976
  int* seg     = (int*)(ws + 1086976);   // (100352+1)*4 pad -> 1488512
  int* eblk    = (int*)(ws + 1488512);   // 12800000 -> 14288512
  int* sortedS = (int*)(ws + 14288512);  // 12800000 -> 27088512 (dead after degout)
  int* sortedE = (int*)(ws + 27088512);  // 12800000 -> 39888512 (dead after fine_sort)
  __half* A1   = (__half*)(ws + 14288512); // alias of sortedS (layer1 gemm out)
  __half* A2   = (__half*)(ws + 27088512); // alias of sortedE (fused agg1+gemm2 out)
  __half* B2   = (__half*)(ws + 14288512); // reuse region1 (A1 dead after agg1)

  zero_k<<<(20992 / 16 + 255) / 256, 256, 0, stream>>>((int4*)ws, 20992 / 16);

  hist_c_k<<<SC_BLOCKS, 256, 0, stream>>>((const int4*)src, (const int4*)dst,
                                          bc_src, bc_dst, tbl_src, tbl_dst);
  scan_c_k<<<1, 256, 0, stream>>>(bc_src, bc_dst, bbase_src, bbase_dst);
  scatter_c_k<<<SC_BLOCKS, 256, 0, stream>>>((const int4*)src, (const int4*)dst,
                                             bbase_src, bbase_dst, tbl_src, tbl_dst,
                                             cur_src, cur_dst, sortedS, sortedE);
  fine_sort_k<<<NBC_USED, 256, 0, stream>>>(sortedE, bbase_dst, deg_in, seg, eblk);
  degout_c_k<<<NBC_USED, 256, 0, stream>>>(sortedS, bbase_src, deg_out);

  const int GEMM_BLKS = (N_NODES + 63) / 64;  // 1563

  // layer 1 GEMM: A1 = fp16((x @ W1) * deg_out^-1/2)
  gemm_tile_k<IN_DIM, float, __half><<<GEMM_BLKS, 256, 0, stream>>>(x, W1, deg_out, A1);
  // fused agg1 + gemm2: A2 = fp16( (relu(agg(A1)*deg_in^-1/2 + b1) @ W2) * deg_out^-1/2 )
  agg_seg_k<true><<<NBLK_AGG, 256, 0, stream>>>(A1, eblk, seg, deg_in, b1, W2, deg_out, A2);
  // agg2: B2 = fp16(relu(agg(A2)*deg_in^-1/2 + b2))
  agg_seg_k<false><<<NBLK_AGG, 256, 0, stream>>>(A2, eblk, seg, deg_in, b2, nullptr, nullptr, B2);

  // pool + heads
  pool_k<<<((N_NODES + 255) / 256 + 3) / 4, 256, 0, stream>>>(B2, node_graph, sums, cnts);
  final_k<<<1, 256, 0, stream>>>(sums, cnts, Wmu, bmu, Wlv, blv, out);
}

// Round 12
// 408.970 us; speedup vs baseline: 1.0807x; 1.0807x over previous
//
#include <hip/hip_runtime.h>
#include <hip/hip_fp16.h>

#define N_NODES 100000
#define N_EDGES 3200000
#define N_GRAPHS 64
#define IN_DIM 128
#define HIDDEN 64
#define LATENT 16

#define NC 256          // coarse dst/src buckets (512 nodes each), node>>9
#define CSHIFT 9
#define NBC_USED 196    // ceil(100000/512)
#define SC_BLOCKS 128
#define NKEYS 4096      // sub(8) x chunk(8) x owner(8) x row(8)
#define NBLK_AGG 1563   // 64-node aggregate blocks
#define NSEG (NBC_USED * 8 * 64)  // 100352 segment offsets

// ---------------- tiny zero kernel ----------------
__global__ __launch_bounds__(256) void zero_k(int4* __restrict__ p, int n4) {
  int i = blockIdx.x * 256 + threadIdx.x;
  if (i < n4) p[i] = make_int4(0, 0, 0, 0);
}

// ---------------- pass A: coarse histograms (256 buckets); dump per-block counts ----
__global__ __launch_bounds__(256) void hist_c_k(const int4* __restrict__ src4,
                                                const int4* __restrict__ dst4,
                                                int* __restrict__ bc_src,
                                                int* __restrict__ bc_dst,
                                                int* __restrict__ tbl_src,
                                                int* __restrict__ tbl_dst) {
  __shared__ int hs[NC], hd[NC];
  int t = threadIdx.x;
  if (t < NC) { hs[t] = 0; hd[t] = 0; }
  __syncthreads();
  const int Q = N_EDGES / 4;
  const int QPB = Q / SC_BLOCKS;
  int q0 = blockIdx.x * QPB, q1 = q0 + QPB;
  for (int i = q0 + t; i < q1; i += 256) {
    int4 s = src4[i], d = dst4[i];
    atomicAdd(&hs[s.x >> CSHIFT], 1); atomicAdd(&hs[s.y >> CSHIFT], 1);
    atomicAdd(&hs[s.z >> CSHIFT], 1); atomicAdd(&hs[s.w >> CSHIFT], 1);
    atomicAdd(&hd[d.x >> CSHIFT], 1); atomicAdd(&hd[d.y >> CSHIFT], 1);
    atomicAdd(&hd[d.z >> CSHIFT], 1); atomicAdd(&hd[d.w >> CSHIFT], 1);
  }
  __syncthreads();
  if (t < NC) {
    int a = hs[t], b = hd[t];
    tbl_src[blockIdx.x * NC + t] = a;
    tbl_dst[blockIdx.x * NC + t] = b;
    if (a) atomicAdd(&bc_src[t], a);
    if (b) atomicAdd(&bc_dst[t], b);
  }
}

// ---------------- pass B: exclusive scan of both 256-entry count arrays ----------------
__global__ __launch_bounds__(256) void scan_c_k(const int* __restrict__ bc_src,
                                                const int* __restrict__ bc_dst,
                                                int* __restrict__ bbase_src,
                                                int* __restrict__ bbase_dst) {
  __shared__ int a[NC], b[NC];
  int t = threadIdx.x;
  int va = bc_src[t], vb = bc_dst[t];
  a[t] = va; b[t] = vb;
  __syncthreads();
  for (int off = 1; off < NC; off <<= 1) {
    int xa = 0, xb = 0;
    if (t >= off) { xa = a[t - off]; xb = b[t - off]; }
    __syncthreads();
    if (t >= off) { a[t] += xa; b[t] += xb; }
    __syncthreads();
  }
  bbase_src[t] = a[t] - va;
  bbase_dst[t] = b[t] - vb;
  if (t == NC - 1) {
    bbase_src[NC] = a[t];
    bbase_dst[NC] = b[t];
  }
}

// ---------------- pass C: coarse scatter (long runs -> low write amplification) ----
__global__ __launch_bounds__(256) void scatter_c_k(const int4* __restrict__ src4,
                                                   const int4* __restrict__ dst4,
                                                   const int* __restrict__ bbase_src,
                                                   const int* __restrict__ bbase_dst,
                                                   const int* __restrict__ tbl_src,
                                                   const int* __restrict__ tbl_dst,
                                                   int* __restrict__ cur_src,
                                                   int* __restrict__ cur_dst,
                                                   int* __restrict__ sortedS,
                                                   int* __restrict__ sortedE) {
  __shared__ int rs[NC], rd[NC];
  int t = threadIdx.x;
  if (t < NC) {
    int a = tbl_src[blockIdx.x * NC + t];
    int b = tbl_dst[blockIdx.x * NC + t];
    rs[t] = a ? (atomicAdd(&cur_src[t], a) + bbase_src[t]) : 0;
    rd[t] = b ? (atomicAdd(&cur_dst[t], b) + bbase_dst[t]) : 0;
  }
  __syncthreads();
  const int Q = N_EDGES / 4;
  const int QPB = Q / SC_BLOCKS;
  int q0 = blockIdx.x * QPB, q1 = q0 + QPB;
  for (int i = q0 + t; i < q1; i += 256) {
    int4 s = src4[i], d = dst4[i];
    int sv[4] = {s.x, s.y, s.z, s.w};
    int dv[4] = {d.x, d.y, d.z, d.w};
#pragma unroll
    for (int k = 0; k < 4; k++) {
      int ps = atomicAdd(&rs[sv[k] >> CSHIFT], 1);
      sortedS[ps] = sv[k];
      int pd = atomicAdd(&rd[dv[k] >> CSHIFT], 1);
      sortedE[pd] = ((dv[k] & 511) << 17) | sv[k];
    }
  }
}

// ---------------- pass D: per-coarse-bucket sort by (sub64, chunk, owner, dstrow) ----
__global__ __launch_bounds__(256) void fine_sort_k(const int* __restrict__ sortedE,
                                                   const int* __restrict__ bbase_dst,
                                                   int* __restrict__ deg_in,
                                                   int* __restrict__ seg,
                                                   int* __restrict__ eblk) {
  __shared__ int hist[NKEYS];         // 16384 B
  __shared__ int cur[NKEYS];          // 16384 B
  __shared__ int ts[256];
  int bk = blockIdx.x, t = threadIdx.x;
  int node0 = bk << CSHIFT;
  int e0 = bbase_dst[bk], e1 = bbase_dst[bk + 1];
  for (int i = t; i < NKEYS; i += 256) hist[i] = 0;
  __syncthreads();
  // key histogram. key = sub*512 + chunk*64 + owner*8 + row
  for (int j = e0 + t; j < e1; j += 256) {
    int v = sortedE[j];
    int d9 = v >> 17, sr = v & 0x1FFFF;
    int key = ((d9 >> 6) << 9) | ((sr >> 14) << 6) | ((d9 & 7) << 3) | ((d9 >> 3) & 7);
    atomicAdd(&hist[key], 1);
  }
  __syncthreads();
  // exclusive scan over 4096 keys (16/thread + block scan)
  int b16 = 16 * t;
  int s = 0;
#pragma unroll
  for (int k = 0; k < 16; k++) s += hist[b16 + k];
  ts[t] = s;
  __syncthreads();
  for (int off = 1; off < 256; off <<= 1) {
    int x = 0;
    if (t >= off) x = ts[t - off];
    __syncthreads();
    if (t >= off) ts[t] += x;
    __syncthreads();
  }
  int run = ts[t] - s;
#pragma unroll
  for (int k = 0; k < 16; k++) { cur[b16 + k] = run; run += hist[b16 + k]; }
  __syncthreads();
  // deg_in (2 nodes per thread)
#pragma unroll
  for (int k = 0; k < 2; k++) {
    int l = t + k * 256;
    int n = node0 + l;
    if (n < N_NODES) {
      int sub = l >> 6, o = l & 7, row = (l >> 3) & 7;
      int base = (sub << 9) | (o << 3) | row;
      int dg = 0;
#pragma unroll
      for (int c = 0; c < 8; c++) dg += hist[base + (c << 6)];
      deg_in[n] = dg;
    }
  }
  // seg offsets: one per (sub, chunk, owner)
  for (int i = t; i < 512; i += 256) {
    int sub = i >> 6, c = (i >> 3) & 7, o = i & 7;
    seg[(bk * 8 + sub) * 64 + c * 8 + o] = e0 + cur[(sub << 9) | (c << 6) | (o << 3)];
  }
  if (bk == NBC_USED - 1 && t == 0) seg[NSEG] = N_EDGES;  // sentinel
  __syncthreads();
  // scatter into eblk (re-read sortedE, L2-hot), repacked as (d6<<17)|src
  for (int j = e0 + t; j < e1; j += 256) {
    int v = sortedE[j];
    int d9 = v >> 17, sr = v & 0x1FFFF;
    int key = ((d9 >> 6) << 9) | ((sr >> 14) << 6) | ((d9 & 7) << 3) | ((d9 >> 3) & 7);
    int pos = e0 + atomicAdd(&cur[key], 1);
    eblk[pos] = ((d9 & 63) << 17) | sr;
  }
}

// ---------------- deg_out: per coarse src-bucket LDS hist over sortedS ----------------
__global__ __launch_bounds__(256) void degout_c_k(const int* __restrict__ sortedS,
                                                  const int* __restrict__ bbase_src,
                                                  int* __restrict__ deg_out) {
  __shared__ int h[512];
  int bk = blockIdx.x, t = threadIdx.x;
  h[t] = 0; h[t + 256] = 0;
  __syncthreads();
  int s0 = bbase_src[bk], s1 = bbase_src[bk + 1];
  for (int j = s0 + t; j < s1; j += 256) atomicAdd(&h[sortedS[j] & 511], 1);
  __syncthreads();
#pragma unroll
  for (int k = 0; k < 2; k++) {
    int l = 2 * t + k;
    int n = (bk << CSHIFT) + l;
    if (n < N_NODES) deg_out[n] = h[l];
  }
}

// ---------------- register-tiled GEMM: out[n][c] = (X@W)[n][c] * rsqrt(max(deg,1)) ----
template <int IN, typename IT, typename OT>
__global__ __launch_bounds__(256) void gemm_tile_k(const IT* __restrict__ X,
                                                   const float* __restrict__ W,
                                                   const int* __restrict__ deg,
                                                   OT* __restrict__ out) {
  __shared__ float xs[64][IN + 4];
  __shared__ float ws[IN][HIDDEN];
  int t = threadIdx.x;
  int row0_blk = blockIdx.x * 64;

  for (int i = t; i < IN * HIDDEN / 4; i += 256)
    ((float4*)ws)[i] = ((const float4*)W)[i];
  for (int i = t; i < 64 * (IN / 4); i += 256) {
    int r = i / (IN / 4), c4 = i % (IN / 4);
    int row = row0_blk + r;
    float4 v = make_float4(0.f, 0.f, 0.f, 0.f);
    if (row < N_NODES) {
      if constexpr (sizeof(IT) == 4) {
        v = *(const float4*)&X[(size_t)row * IN + c4 * 4];
      } else {
        union { short4 s; __half2 h2[2]; } u;
        u.s = *(const short4*)&X[(size_t)row * IN + c4 * 4];
        float2 f0 = __half22float2(u.h2[0]);
        float2 f1 = __half22float2(u.h2[1]);
        v = make_float4(f0.x, f0.y, f1.x, f1.y);
      }
    }
    *(float4*)&xs[r][c4 * 4] = v;
  }
  __syncthreads();

  int w = t >> 6, lane = t & 63;
  int rg = lane >> 4, cg = lane & 15;
  int r0 = w * 16 + rg * 4;
  int c0 = cg * 4;

  float acc[4][4];
#pragma unroll
  for (int i = 0; i < 4; i++)
#pragma unroll
    for (int j = 0; j < 4; j++) acc[i][j] = 0.f;

#pragma unroll 4
  for (int d4 = 0; d4 < IN / 4; d4++) {
    float4 a0 = *(const float4*)&xs[r0 + 0][d4 * 4];
    float4 a1 = *(const float4*)&xs[r0 + 1][d4 * 4];
    float4 a2 = *(const float4*)&xs[r0 + 2][d4 * 4];
    float4 a3 = *(const float4*)&xs[r0 + 3][d4 * 4];
#pragma unroll
    for (int dd = 0; dd < 4; dd++) {
      float4 b = *(const float4*)&ws[d4 * 4 + dd][c0];
      float av0 = (&a0.x)[dd], av1 = (&a1.x)[dd], av2 = (&a2.x)[dd], av3 = (&a3.x)[dd];
      acc[0][0] += av0 * b.x; acc[0][1] += av0 * b.y; acc[0][2] += av0 * b.z; acc[0][3] += av0 * b.w;
      acc[1][0] += av1 * b.x; acc[1][1] += av1 * b.y; acc[1][2] += av1 * b.z; acc[1][3] += av1 * b.w;
      acc[2][0] += av2 * b.x; acc[2][1] += av2 * b.y; acc[2][2] += av2 * b.z; acc[2][3] += av2 * b.w;
      acc[3][0] += av3 * b.x; acc[3][1] += av3 * b.y; acc[3][2] += av3 * b.z; acc[3][3] += av3 * b.w;
    }
  }

#pragma unroll
  for (int i = 0; i < 4; i++) {
    int row = row0_blk + r0 + i;
    if (row >= N_NODES) continue;
    float dg = (float)deg[row];
    if (dg < 1.f) dg = 1.f;
    float sc = rsqrtf(dg);
    if constexpr (sizeof(OT) == 2) {
      __half2 p0 = __floats2half2_rn(acc[i][0] * sc, acc[i][1] * sc);
      __half2 p1 = __floats2half2_rn(acc[i][2] * sc, acc[i][3] * sc);
      union { __half2 h2[2]; float2 f2; } u;
      u.h2[0] = p0; u.h2[1] = p1;
      *(float2*)&out[(size_t)row * HIDDEN + c0] = u.f2;
    } else {
      float4 o = make_float4(acc[i][0] * sc, acc[i][1] * sc, acc[i][2] * sc, acc[i][3] * sc);
      *(float4*)&out[(size_t)row * HIDDEN + c0] = o;
    }
  }
}

// ---------------- aggregate: block=64 dst nodes, chunk-swept, owner-exclusive LDS ----
// FUSE: fused gemm2 reads W2 DIRECTLY FROM GLOBAL (L1-resident 16KB) -- no extra
// LDS, so LDS stays 17.4KB -> 8 blocks/CU -> all 1563 blocks co-resident (phase
// alignment of the chunk sweep depends on this; R11's ws2 staging broke it).
template <bool FUSE>
__global__ __launch_bounds__(256) void agg_seg_k(const __half* __restrict__ A,
                                                 const int* __restrict__ eblk,
                                                 const int* __restrict__ seg,
                                                 const int* __restrict__ deg_in,
                                                 const float* __restrict__ bias,
                                                 const float* __restrict__ W2,
                                                 const int* __restrict__ deg_out,
                                                 __half* __restrict__ out) {
  __shared__ float acc[64][68];   // 17408 B (stride 68: 16B-aligned float4 rows)
  int bk = blockIdx.x, t = threadIdx.x;
  int o = t >> 5, l = t & 31;  // half-wave owner (0..7), lane covers 2 channels
  for (int i = t; i < 64 * 68; i += 256) ((float*)acc)[i] = 0.f;
  __syncthreads();
  int segbase = bk * 64;
  float rx = 0.f, ry = 0.f;
  int cur_d = -1;
#pragma unroll
  for (int c = 0; c < 8; c++) {
    int j0 = seg[segbase + c * 8 + o];
    int j1 = seg[segbase + c * 8 + o + 1];
    int j = j0;
    for (; j + 16 <= j1; j += 16) {
      int vv[16];
#pragma unroll
      for (int k = 0; k < 16; k++) vv[k] = eblk[j + k];
      float2 ff[16];
#pragma unroll
      for (int k = 0; k < 16; k++)
        ff[k] = __half22float2(*(const __half2*)&A[(size_t)(vv[k] & 0x1FFFF) * HIDDEN + 2 * l]);
#pragma unroll
      for (int k = 0; k < 16; k++) {
        int d = vv[k] >> 17;
        if (d != cur_d) {
          if (cur_d >= 0) {
            float2* ap = (float2*)&acc[cur_d][2 * l];
            float2 a0 = *ap; a0.x += rx; a0.y += ry; *ap = a0;
          }
          cur_d = d; rx = 0.f; ry = 0.f;
        }
        rx += ff[k].x; ry += ff[k].y;
      }
    }
    for (; j + 4 <= j1; j += 4) {
      int vv[4];
#pragma unroll
      for (int k = 0; k < 4; k++) vv[k] = eblk[j + k];
      float2 ff[4];
#pragma unroll
      for (int k = 0; k < 4; k++)
        ff[k] = __half22float2(*(const __half2*)&A[(size_t)(vv[k] & 0x1FFFF) * HIDDEN + 2 * l]);
#pragma unroll
      for (int k = 0; k < 4; k++) {
        int d = vv[k] >> 17;
        if (d != cur_d) {
          if (cur_d >= 0) {
            float2* ap = (float2*)&acc[cur_d][2 * l];
            float2 a0 = *ap; a0.x += rx; a0.y += ry; *ap = a0;
          }
          cur_d = d; rx = 0.f; ry = 0.f;
        }
        rx += ff[k].x; ry += ff[k].y;
      }
    }
    for (; j < j1; j++) {
      int v = eblk[j];
      int d = v >> 17;
      if (d != cur_d) {
        if (cur_d >= 0) {
          float2* ap = (float2*)&acc[cur_d][2 * l];
          float2 a0 = *ap; a0.x += rx; a0.y += ry; *ap = a0;
        }
        cur_d = d; rx = 0.f; ry = 0.f;
      }
      float2 f = __half22float2(*(const __half2*)&A[(size_t)(v & 0x1FFFF) * HIDDEN + 2 * l]);
      rx += f.x; ry += f.y;
    }
  }
  if (cur_d >= 0) {
    float2* ap = (float2*)&acc[cur_d][2 * l];
    float2 a0 = *ap; a0.x += rx; a0.y += ry; *ap = a0;
  }
  __syncthreads();

  int node0 = bk << 6;
  if constexpr (!FUSE) {
    // writeout: scale + bias + relu -> fp16
    for (int i = t; i < 64 * 64; i += 256) {
      int r = i >> 6, ch = i & 63;
      int node = node0 + r;
      if (node >= N_NODES) continue;
      float dg = (float)deg_in[node];
      if (dg < 1.f) dg = 1.f;
      float v = acc[r][ch] * rsqrtf(dg) + bias[ch];
      out[(size_t)node * HIDDEN + ch] = __float2half(v > 0.f ? v : 0.f);
    }
  } else {
    // B = relu(scale + bias) in place (f32)
    for (int i = t; i < 64 * 64; i += 256) {
      int r = i >> 6, ch = i & 63;
      float dg = (float)deg_in[node0 + r];  // alloc padded; garbage rows unused
      if (dg < 1.f) dg = 1.f;
      float v = acc[r][ch] * rsqrtf(dg) + bias[ch];
      acc[r][ch] = v > 0.f ? v : 0.f;
    }
    __syncthreads();
    // fused gemm2: out[n][c2] = (sum_c B[n][c] * W2[c][c2]) * rsqrt(deg_out[n])
    int w = t >> 6, lane = t & 63;
    int rg = lane >> 4, cg = lane & 15;
    int r0 = w * 16 + rg * 4;
    int c0 = cg * 4;
    float oacc[4][4];
#pragma unroll
    for (int i = 0; i < 4; i++)
#pragma unroll
      for (int j = 0; j < 4; j++) oacc[i][j] = 0.f;
#pragma unroll 4
    for (int d = 0; d < 64; d++) {
      float4 b = *(const float4*)&W2[d * HIDDEN + c0];  // global, L1-resident
      float a0 = acc[r0 + 0][d], a1 = acc[r0 + 1][d];
      float a2 = acc[r0 + 2][d], a3 = acc[r0 + 3][d];
      oacc[0][0] += a0 * b.x; oacc[0][1] += a0 * b.y; oacc[0][2] += a0 * b.z; oacc[0][3] += a0 * b.w;
      oacc[1][0] += a1 * b.x; oacc[1][1] += a1 * b.y; oacc[1][2] += a1 * b.z; oacc[1][3] += a1 * b.w;
      oacc[2][0] += a2 * b.x; oacc[2][1] += a2 * b.y; oacc[2][2] += a2 * b.z; oacc[2][3] += a2 * b.w;
      oacc[3][0] += a3 * b.x; oacc[3][1] += a3 * b.y; oacc[3][2] += a3 * b.z; oacc[3][3] += a3 * b.w;
    }
#pragma unroll
    for (int i = 0; i < 4; i++) {
      int node = node0 + r0 + i;
      if (node >= N_NODES) continue;
      float dg = (float)deg_out[node];
      if (dg < 1.f) dg = 1.f;
      float sc = rsqrtf(dg);
      __half2 p0 = __floats2half2_rn(oacc[i][0] * sc, oacc[i][1] * sc);
      __half2 p1 = __floats2half2_rn(oacc[i][2] * sc, oacc[i][3] * sc);
      union { __half2 h2[2]; float2 f2; } u;
      u.h2[0] = p0; u.h2[1] = p1;
      *(float2*)&out[(size_t)node * HIDDEN + c0] = u.f2;
    }
  }
}

// ---------------- per-graph mean pool (sorted node_graph, run-accumulate) ----------------
__global__ __launch_bounds__(256) void pool_k(const __half* __restrict__ h,
                                              const int* __restrict__ node_graph,
                                              float* __restrict__ sums,
                                              float* __restrict__ counts) {
  const int NPW = 256;
  int wave = (int)((blockIdx.x * blockDim.x + threadIdx.x) >> 6);
  int lane = threadIdx.x & 63;
  int start = wave * NPW;
  if (start >= N_NODES) return;
  int end = start + NPW; if (end > N_NODES) end = N_NODES;
  int cur = node_graph[start];
  float acc = 0.f, cnt = 0.f;
  for (int n = start; n < end; n++) {
    int g = node_graph[n];
    if (g != cur) {
      atomicAdd(&sums[cur * HIDDEN + lane], acc);
      if (lane == 0) atomicAdd(&counts[cur], cnt);
      cur = g; acc = 0.f; cnt = 0.f;
    }
    acc += __half2float(h[(size_t)n * HIDDEN + lane]);
    cnt += 1.f;
  }
  atomicAdd(&sums[cur * HIDDEN + lane], acc);
  if (lane == 0) atomicAdd(&counts[cur], cnt);
}

// ---------------- final: h_graph = sums/counts; mu/logvar = h_graph @ Wmu/Wlv + b ----------------
__global__ __launch_bounds__(256) void final_k(const float* __restrict__ sums,
                                               const float* __restrict__ counts,
                                               const float* __restrict__ Wmu,
                                               const float* __restrict__ bmu,
                                               const float* __restrict__ Wlv,
                                               const float* __restrict__ blv,
                                               float* __restrict__ out) {
  __shared__ float hg[N_GRAPHS][HIDDEN];
  __shared__ float wmu[HIDDEN][LATENT];
  __shared__ float wlv[HIDDEN][LATENT];
  int t = threadIdx.x;
  for (int i = t; i < N_GRAPHS * HIDDEN; i += 256) {
    int g = i / HIDDEN;
    float c = counts[g];
    if (c < 1.f) c = 1.f;
    hg[g][i % HIDDEN] = sums[i] / c;
  }
  for (int i = t; i < HIDDEN * LATENT; i += 256) {
    wmu[i / LATENT][i % LATENT] = Wmu[i];
    wlv[i / LATENT][i % LATENT] = Wlv[i];
  }
  __syncthreads();
  for (int i = t; i < N_GRAPHS * LATENT; i += 256) {
    int g = i / LATENT, j = i % LATENT;
    float mu = bmu[j], lv = blv[j];
#pragma unroll
    for (int k = 0; k < HIDDEN; k++) {
      float v = hg[g][k];
      mu += v * wmu[k][j];
      lv += v * wlv[k][j];
    }
    out[i] = mu;
    out[N_GRAPHS * LATENT + i] = lv;
  }
}

extern "C" void kernel_launch(void* const* d_in, const int* in_sizes, int n_in,
                              void* d_out, int out_size, void* d_ws, size_t ws_size,
                              hipStream_t stream) {
  const float* x = (const float*)d_in[0];
  // d_in[1] = edge_feat: provably unused for (mu, logvar)
  const int* src = (const int*)d_in[2];
  const int* dst = (const int*)d_in[3];
  const int* node_graph = (const int*)d_in[4];
  const float* W1 = (const float*)d_in[5];
  const float* b1 = (const float*)d_in[6];
  const float* W2 = (const float*)d_in[7];
  const float* b2 = (const float*)d_in[8];
  // d_in[9] = We, d_in[10] = be: unused
  const float* Wmu = (const float*)d_in[11];
  const float* bmu = (const float*)d_in[12];
  const float* Wlv = (const float*)d_in[13];
  const float* blv = (const float*)d_in[14];
  float* out = (float*)d_out;

  char* ws = (char*)d_ws;
  // zeroed control block [0, 20992)
  int* bc_src   = (int*)(ws + 0);        // 1024
  int* bc_dst   = (int*)(ws + 1024);     // 1024
  int* cur_src  = (int*)(ws + 2048);     // 1024
  int* cur_dst  = (int*)(ws + 3072);     // 1024
  float* cnts   = (float*)(ws + 4096);   // 512
  float* sums   = (float*)(ws + 4608);   // 16384 -> 20992
  // non-zeroed control
  int* bbase_src = (int*)(ws + 21504);   // 1028 (pad)
  int* bbase_dst = (int*)(ws + 22784);   // 1028 (pad)
  int* tbl_src   = (int*)(ws + 24576);   // 131072
  int* tbl_dst   = (int*)(ws + 155648);  // 131072 -> 286720
  // big arrays
  int* deg_out = (int*)(ws + 286720);    // 400128 -> 686848
  int* deg_in  = (int*)(ws + 686848);    // 400128 -> 1086976
  int* seg     = (int*)(ws + 1086976);   // (100352+1)*4 pad -> 1488512
  int* eblk    = (int*)(ws + 1488512);   // 12800000 -> 14288512
  int* sortedS = (int*)(ws + 14288512);  // 12800000 -> 27088512 (dead after degout)
  int* sortedE = (int*)(ws + 27088512);  // 12800000 -> 39888512 (dead after fine_sort)
  __half* A1   = (__half*)(ws + 14288512); // alias of sortedS (layer1 gemm out)
  __half* A2   = (__half*)(ws + 27088512); // alias of sortedE (fused agg1+gemm2 out)
  __half* B2   = (__half*)(ws + 14288512); // reuse region1 (A1 dead after agg1)

  zero_k<<<(20992 / 16 + 255) / 256, 256, 0, stream>>>((int4*)ws, 20992 / 16);

  hist_c_k<<<SC_BLOCKS, 256, 0, stream>>>((const int4*)src, (const int4*)dst,
                                          bc_src, bc_dst, tbl_src, tbl_dst);
  scan_c_k<<<1, 256, 0, stream>>>(bc_src, bc_dst, bbase_src, bbase_dst);
  scatter_c_k<<<SC_BLOCKS, 256, 0, stream>>>((const int4*)src, (const int4*)dst,
                                             bbase_src, bbase_dst, tbl_src, tbl_dst,
                                             cur_src, cur_dst, sortedS, sortedE);
  fine_sort_k<<<NBC_USED, 256, 0, stream>>>(sortedE, bbase_dst, deg_in, seg, eblk);
  degout_c_k<<<NBC_USED, 256, 0, stream>>>(sortedS, bbase_src, deg_out);

  const int GEMM_BLKS = (N_NODES + 63) / 64;  // 1563

  // layer 1 GEMM: A1 = fp16((x @ W1) * deg_out^-1/2)
  gemm_tile_k<IN_DIM, float, __half><<<GEMM_BLKS, 256, 0, stream>>>(x, W1, deg_out, A1);
  // fused agg1 + gemm2: A2 = fp16( (relu(agg(A1)*deg_in^-1/2 + b1) @ W2) * deg_out^-1/2 )
  agg_seg_k<true><<<NBLK_AGG, 256, 0, stream>>>(A1, eblk, seg, deg_in, b1, W2, deg_out, A2);
  // agg2: B2 = fp16(relu(agg(A2)*deg_in^-1/2 + b2))
  agg_seg_k<false><<<NBLK_AGG, 256, 0, stream>>>(A2, eblk, seg, deg_in, b2, nullptr, nullptr, B2);

  // pool + heads
  pool_k<<<((N_NODES + 255) / 256 + 3) / 4, 256, 0, stream>>>(B2, node_graph, sums, cnts);
  final_k<<<1, 256, 0, stream>>>(sums, cnts, Wmu, bmu, Wlv, blv, out);
}

// Round 13
// 363.228 us; speedup vs baseline: 1.2167x; 1.1259x over previous
//
#include <hip/hip_runtime.h>
#include <hip/hip_fp16.h>

#define N_NODES 100000
#define N_EDGES 3200000
#define N_GRAPHS 64
#define IN_DIM 128
#define HIDDEN 64
#define LATENT 16

#define NC 256          // coarse dst/src buckets (512 nodes each), node>>9
#define CSHIFT 9
#define NBC_USED 196    // ceil(100000/512)
#define SC_BLOCKS 256   // full GPU for hist/scatter (was 128 = half idle)
#define NKEYS 4096      // sub(8) x chunk(8) x owner(8) x row(8)
#define NBLK_AGG 1563   // 64-node aggregate blocks
#define NSEG (NBC_USED * 8 * 64)  // 100352 segment offsets

// ---------------- tiny zero kernel ----------------
__global__ __launch_bounds__(256) void zero_k(int4* __restrict__ p, int n4) {
  int i = blockIdx.x * 256 + threadIdx.x;
  if (i < n4) p[i] = make_int4(0, 0, 0, 0);
}

// ---------------- pass A: coarse histograms (256 buckets); dump per-block counts ----
__global__ __launch_bounds__(256) void hist_c_k(const int4* __restrict__ src4,
                                                const int4* __restrict__ dst4,
                                                int* __restrict__ bc_src,
                                                int* __restrict__ bc_dst,
                                                int* __restrict__ tbl_src,
                                                int* __restrict__ tbl_dst) {
  __shared__ int hs[NC], hd[NC];
  int t = threadIdx.x;
  if (t < NC) { hs[t] = 0; hd[t] = 0; }
  __syncthreads();
  const int Q = N_EDGES / 4;
  const int QPB = Q / SC_BLOCKS;   // 3125
  int q0 = blockIdx.x * QPB, q1 = q0 + QPB;
  for (int i = q0 + t; i < q1; i += 256) {
    int4 s = src4[i], d = dst4[i];
    atomicAdd(&hs[s.x >> CSHIFT], 1); atomicAdd(&hs[s.y >> CSHIFT], 1);
    atomicAdd(&hs[s.z >> CSHIFT], 1); atomicAdd(&hs[s.w >> CSHIFT], 1);
    atomicAdd(&hd[d.x >> CSHIFT], 1); atomicAdd(&hd[d.y >> CSHIFT], 1);
    atomicAdd(&hd[d.z >> CSHIFT], 1); atomicAdd(&hd[d.w >> CSHIFT], 1);
  }
  __syncthreads();
  if (t < NC) {
    int a = hs[t], b = hd[t];
    tbl_src[blockIdx.x * NC + t] = a;
    tbl_dst[blockIdx.x * NC + t] = b;
    if (a) atomicAdd(&bc_src[t], a);
    if (b) atomicAdd(&bc_dst[t], b);
  }
}

// ---------------- pass B: exclusive scan of both 256-entry count arrays ----------------
__global__ __launch_bounds__(256) void scan_c_k(const int* __restrict__ bc_src,
                                                const int* __restrict__ bc_dst,
                                                int* __restrict__ bbase_src,
                                                int* __restrict__ bbase_dst) {
  __shared__ int a[NC], b[NC];
  int t = threadIdx.x;
  int va = bc_src[t], vb = bc_dst[t];
  a[t] = va; b[t] = vb;
  __syncthreads();
  for (int off = 1; off < NC; off <<= 1) {
    int xa = 0, xb = 0;
    if (t >= off) { xa = a[t - off]; xb = b[t - off]; }
    __syncthreads();
    if (t >= off) { a[t] += xa; b[t] += xb; }
    __syncthreads();
  }
  bbase_src[t] = a[t] - va;
  bbase_dst[t] = b[t] - vb;
  if (t == NC - 1) {
    bbase_src[NC] = a[t];
    bbase_dst[NC] = b[t];
  }
}

// ---------------- pass C: coarse scatter (long runs -> low write amplification) ----
__global__ __launch_bounds__(256) void scatter_c_k(const int4* __restrict__ src4,
                                                   const int4* __restrict__ dst4,
                                                   const int* __restrict__ bbase_src,
                                                   const int* __restrict__ bbase_dst,
                                                   const int* __restrict__ tbl_src,
                                                   const int* __restrict__ tbl_dst,
                                                   int* __restrict__ cur_src,
                                                   int* __restrict__ cur_dst,
                                                   int* __restrict__ sortedS,
                                                   int* __restrict__ sortedE) {
  __shared__ int rs[NC], rd[NC];
  int t = threadIdx.x;
  if (t < NC) {
    int a = tbl_src[blockIdx.x * NC + t];
    int b = tbl_dst[blockIdx.x * NC + t];
    rs[t] = a ? (atomicAdd(&cur_src[t], a) + bbase_src[t]) : 0;
    rd[t] = b ? (atomicAdd(&cur_dst[t], b) + bbase_dst[t]) : 0;
  }
  __syncthreads();
  const int Q = N_EDGES / 4;
  const int QPB = Q / SC_BLOCKS;
  int q0 = blockIdx.x * QPB, q1 = q0 + QPB;
  for (int i = q0 + t; i < q1; i += 256) {
    int4 s = src4[i], d = dst4[i];
    int sv[4] = {s.x, s.y, s.z, s.w};
    int dv[4] = {d.x, d.y, d.z, d.w};
#pragma unroll
    for (int k = 0; k < 4; k++) {
      int ps = atomicAdd(&rs[sv[k] >> CSHIFT], 1);
      sortedS[ps] = sv[k];
      int pd = atomicAdd(&rd[dv[k] >> CSHIFT], 1);
      sortedE[pd] = ((dv[k] & 511) << 17) | sv[k];
    }
  }
}

// ---------------- pass D: per-coarse-bucket sort by (sub64, chunk, owner, dstrow) ----
__global__ __launch_bounds__(256) void fine_sort_k(const int* __restrict__ sortedE,
                                                   const int* __restrict__ bbase_dst,
                                                   int* __restrict__ deg_in,
                                                   int* __restrict__ seg,
                                                   int* __restrict__ eblk) {
  __shared__ int hist[NKEYS];         // 16384 B
  __shared__ int cur[NKEYS];          // 16384 B
  __shared__ int ts[256];
  int bk = blockIdx.x, t = threadIdx.x;
  int node0 = bk << CSHIFT;
  int e0 = bbase_dst[bk], e1 = bbase_dst[bk + 1];
  for (int i = t; i < NKEYS; i += 256) hist[i] = 0;
  __syncthreads();
  // key histogram. key = sub*512 + chunk*64 + owner*8 + row
  for (int j = e0 + t; j < e1; j += 256) {
    int v = sortedE[j];
    int d9 = v >> 17, sr = v & 0x1FFFF;
    int key = ((d9 >> 6) << 9) | ((sr >> 14) << 6) | ((d9 & 7) << 3) | ((d9 >> 3) & 7);
    atomicAdd(&hist[key], 1);
  }
  __syncthreads();
  // exclusive scan over 4096 keys (16/thread + block scan)
  int b16 = 16 * t;
  int s = 0;
#pragma unroll
  for (int k = 0; k < 16; k++) s += hist[b16 + k];
  ts[t] = s;
  __syncthreads();
  for (int off = 1; off < 256; off <<= 1) {
    int x = 0;
    if (t >= off) x = ts[t - off];
    __syncthreads();
    if (t >= off) ts[t] += x;
    __syncthreads();
  }
  int run = ts[t] - s;
#pragma unroll
  for (int k = 0; k < 16; k++) { cur[b16 + k] = run; run += hist[b16 + k]; }
  __syncthreads();
  // deg_in (2 nodes per thread)
#pragma unroll
  for (int k = 0; k < 2; k++) {
    int l = t + k * 256;
    int n = node0 + l;
    if (n < N_NODES) {
      int sub = l >> 6, o = l & 7, row = (l >> 3) & 7;
      int base = (sub << 9) | (o << 3) | row;
      int dg = 0;
#pragma unroll
      for (int c = 0; c < 8; c++) dg += hist[base + (c << 6)];
      deg_in[n] = dg;
    }
  }
  // seg offsets: one per (sub, chunk, owner)
  for (int i = t; i < 512; i += 256) {
    int sub = i >> 6, c = (i >> 3) & 7, o = i & 7;
    seg[(bk * 8 + sub) * 64 + c * 8 + o] = e0 + cur[(sub << 9) | (c << 6) | (o << 3)];
  }
  if (bk == NBC_USED - 1 && t == 0) seg[NSEG] = N_EDGES;  // sentinel
  __syncthreads();
  // scatter into eblk (re-read sortedE, L2-hot), repacked as (d6<<17)|src
  for (int j = e0 + t; j < e1; j += 256) {
    int v = sortedE[j];
    int d9 = v >> 17, sr = v & 0x1FFFF;
    int key = ((d9 >> 6) << 9) | ((sr >> 14) << 6) | ((d9 & 7) << 3) | ((d9 >> 3) & 7);
    int pos = e0 + atomicAdd(&cur[key], 1);
    eblk[pos] = ((d9 & 63) << 17) | sr;
  }
}

// ---------------- deg_out: per coarse src-bucket LDS hist over sortedS ----------------
__global__ __launch_bounds__(256) void degout_c_k(const int* __restrict__ sortedS,
                                                  const int* __restrict__ bbase_src,
                                                  int* __restrict__ deg_out) {
  __shared__ int h[512];
  int bk = blockIdx.x, t = threadIdx.x;
  h[t] = 0; h[t + 256] = 0;
  __syncthreads();
  int s0 = bbase_src[bk], s1 = bbase_src[bk + 1];
  for (int j = s0 + t; j < s1; j += 256) atomicAdd(&h[sortedS[j] & 511], 1);
  __syncthreads();
#pragma unroll
  for (int k = 0; k < 2; k++) {
    int l = 2 * t + k;
    int n = (bk << CSHIFT) + l;
    if (n < N_NODES) deg_out[n] = h[l];
  }
}

// ---------------- per-graph node counts (node_graph is sorted, but hist is simplest) ----
__global__ __launch_bounds__(256) void counts_k(const int* __restrict__ node_graph,
                                                float* __restrict__ counts) {
  __shared__ int h[N_GRAPHS];
  int t = threadIdx.x;
  if (t < N_GRAPHS) h[t] = 0;
  __syncthreads();
  int base = blockIdx.x * 1024;
  int end = base + 1024; if (end > N_NODES) end = N_NODES;
  for (int i = base + t; i < end; i += 256) atomicAdd(&h[node_graph[i]], 1);
  __syncthreads();
  if (t < N_GRAPHS && h[t]) atomicAdd(&counts[t], (float)h[t]);
}

// ---------------- register-tiled GEMM: out[n][c] = (X@W)[n][c] * rsqrt(max(deg,1)) ----
template <int IN, typename IT, typename OT>
__global__ __launch_bounds__(256) void gemm_tile_k(const IT* __restrict__ X,
                                                   const float* __restrict__ W,
                                                   const int* __restrict__ deg,
                                                   OT* __restrict__ out) {
  __shared__ float xs[64][IN + 4];
  __shared__ float ws[IN][HIDDEN];
  int t = threadIdx.x;
  int row0_blk = blockIdx.x * 64;

  for (int i = t; i < IN * HIDDEN / 4; i += 256)
    ((float4*)ws)[i] = ((const float4*)W)[i];
  for (int i = t; i < 64 * (IN / 4); i += 256) {
    int r = i / (IN / 4), c4 = i % (IN / 4);
    int row = row0_blk + r;
    float4 v = make_float4(0.f, 0.f, 0.f, 0.f);
    if (row < N_NODES) {
      if constexpr (sizeof(IT) == 4) {
        v = *(const float4*)&X[(size_t)row * IN + c4 * 4];
      } else {
        union { short4 s; __half2 h2[2]; } u;
        u.s = *(const short4*)&X[(size_t)row * IN + c4 * 4];
        float2 f0 = __half22float2(u.h2[0]);
        float2 f1 = __half22float2(u.h2[1]);
        v = make_float4(f0.x, f0.y, f1.x, f1.y);
      }
    }
    *(float4*)&xs[r][c4 * 4] = v;
  }
  __syncthreads();

  int w = t >> 6, lane = t & 63;
  int rg = lane >> 4, cg = lane & 15;
  int r0 = w * 16 + rg * 4;
  int c0 = cg * 4;

  float acc[4][4];
#pragma unroll
  for (int i = 0; i < 4; i++)
#pragma unroll
    for (int j = 0; j < 4; j++) acc[i][j] = 0.f;

#pragma unroll 4
  for (int d4 = 0; d4 < IN / 4; d4++) {
    float4 a0 = *(const float4*)&xs[r0 + 0][d4 * 4];
    float4 a1 = *(const float4*)&xs[r0 + 1][d4 * 4];
    float4 a2 = *(const float4*)&xs[r0 + 2][d4 * 4];
    float4 a3 = *(const float4*)&xs[r0 + 3][d4 * 4];
#pragma unroll
    for (int dd = 0; dd < 4; dd++) {
      float4 b = *(const float4*)&ws[d4 * 4 + dd][c0];
      float av0 = (&a0.x)[dd], av1 = (&a1.x)[dd], av2 = (&a2.x)[dd], av3 = (&a3.x)[dd];
      acc[0][0] += av0 * b.x; acc[0][1] += av0 * b.y; acc[0][2] += av0 * b.z; acc[0][3] += av0 * b.w;
      acc[1][0] += av1 * b.x; acc[1][1] += av1 * b.y; acc[1][2] += av1 * b.z; acc[1][3] += av1 * b.w;
      acc[2][0] += av2 * b.x; acc[2][1] += av2 * b.y; acc[2][2] += av2 * b.z; acc[2][3] += av2 * b.w;
      acc[3][0] += av3 * b.x; acc[3][1] += av3 * b.y; acc[3][2] += av3 * b.z; acc[3][3] += av3 * b.w;
    }
  }

#pragma unroll
  for (int i = 0; i < 4; i++) {
    int row = row0_blk + r0 + i;
    if (row >= N_NODES) continue;
    float dg = (float)deg[row];
    if (dg < 1.f) dg = 1.f;
    float sc = rsqrtf(dg);
    if constexpr (sizeof(OT) == 2) {
      __half2 p0 = __floats2half2_rn(acc[i][0] * sc, acc[i][1] * sc);
      __half2 p1 = __floats2half2_rn(acc[i][2] * sc, acc[i][3] * sc);
      union { __half2 h2[2]; float2 f2; } u;
      u.h2[0] = p0; u.h2[1] = p1;
      *(float2*)&out[(size_t)row * HIDDEN + c0] = u.f2;
    } else {
      float4 o = make_float4(acc[i][0] * sc, acc[i][1] * sc, acc[i][2] * sc, acc[i][3] * sc);
      *(float4*)&out[(size_t)row * HIDDEN + c0] = o;
    }
  }
}

// ---------------- aggregate: block=64 dst nodes, chunk-swept, owner-exclusive LDS ----
// eblk words are loaded 16-at-a-time with ONE coalesced 64B load + __shfl(.,k,32)
// (replaces 16 broadcast 4B VMEMs). MODE 1: fuse gemm2 (W2 from global, L1-hot),
// write A2. MODE 2: fuse mean-pool partial sums (no per-node output at all).
// LDS stays ~17.7KB -> 8 blocks/CU -> all 1563 blocks co-resident (required for
// the lockstep chunk sweep; see R11 post-mortem).
template <int MODE>
__global__ __launch_bounds__(256) void agg_seg_k(const __half* __restrict__ A,
                                                 const int* __restrict__ eblk,
                                                 const int* __restrict__ seg,
                                                 const int* __restrict__ deg_in,
                                                 const float* __restrict__ bias,
                                                 const float* __restrict__ W2,
                                                 const int* __restrict__ deg_out,
                                                 const int* __restrict__ node_graph,
                                                 float* __restrict__ sums,
                                                 __half* __restrict__ out) {
  __shared__ float acc[64][68];   // 17408 B (stride 68: 16B-aligned float4 rows)
  __shared__ int ngs[64];
  __shared__ float psum[4][64];
  int bk = blockIdx.x, t = threadIdx.x;
  int o = t >> 5, l = t & 31;  // half-wave owner (0..7), lane covers 2 channels
  for (int i = t; i < 64 * 68; i += 256) ((float*)acc)[i] = 0.f;
  __syncthreads();
  int segbase = bk * 64;
  float rx = 0.f, ry = 0.f;
  int cur_d = -1;
#pragma unroll
  for (int c = 0; c < 8; c++) {
    int j0 = seg[segbase + c * 8 + o];
    int j1 = seg[segbase + c * 8 + o + 1];
    int j = j0;
    for (; j + 16 <= j1; j += 16) {
      int ev = eblk[j + (l & 15)];   // one coalesced 64B load per halfwave
      int vv[16];
#pragma unroll
      for (int k = 0; k < 16; k++) vv[k] = __shfl(ev, k, 32);
      float2 ff[16];
#pragma unroll
      for (int k = 0; k < 16; k++)
        ff[k] = __half22float2(*(const __half2*)&A[(size_t)(vv[k] & 0x1FFFF) * HIDDEN + 2 * l]);
#pragma unroll
      for (int k = 0; k < 16; k++) {
        int d = vv[k] >> 17;
        if (d != cur_d) {
          if (cur_d >= 0) {
            float2* ap = (float2*)&acc[cur_d][2 * l];
            float2 a0 = *ap; a0.x += rx; a0.y += ry; *ap = a0;
          }
          cur_d = d; rx = 0.f; ry = 0.f;
        }
        rx += ff[k].x; ry += ff[k].y;
      }
    }
    for (; j + 4 <= j1; j += 4) {
      int vv[4];
#pragma unroll
      for (int k = 0; k < 4; k++) vv[k] = eblk[j + k];
      float2 ff[4];
#pragma unroll
      for (int k = 0; k < 4; k++)
        ff[k] = __half22float2(*(const __half2*)&A[(size_t)(vv[k] & 0x1FFFF) * HIDDEN + 2 * l]);
#pragma unroll
      for (int k = 0; k < 4; k++) {
        int d = vv[k] >> 17;
        if (d != cur_d) {
          if (cur_d >= 0) {
            float2* ap = (float2*)&acc[cur_d][2 * l];
            float2 a0 = *ap; a0.x += rx; a0.y += ry; *ap = a0;
          }
          cur_d = d; rx = 0.f; ry = 0.f;
        }
        rx += ff[k].x; ry += ff[k].y;
      }
    }
    for (; j < j1; j++) {
      int v = eblk[j];
      int d = v >> 17;
      if (d != cur_d) {
        if (cur_d >= 0) {
          float2* ap = (float2*)&acc[cur_d][2 * l];
          float2 a0 = *ap; a0.x += rx; a0.y += ry; *ap = a0;
        }
        cur_d = d; rx = 0.f; ry = 0.f;
      }
      float2 f = __half22float2(*(const __half2*)&A[(size_t)(v & 0x1FFFF) * HIDDEN + 2 * l]);
      rx += f.x; ry += f.y;
    }
  }
  if (cur_d >= 0) {
    float2* ap = (float2*)&acc[cur_d][2 * l];
    float2 a0 = *ap; a0.x += rx; a0.y += ry; *ap = a0;
  }
  __syncthreads();

  int node0 = bk << 6;
  if constexpr (MODE == 1) {
    // B = relu(scale + bias) in place (f32)
    for (int i = t; i < 64 * 64; i += 256) {
      int r = i >> 6, ch = i & 63;
      float dg = (float)deg_in[node0 + r];  // deg_in padded to 100032; garbage rows unused
      if (dg < 1.f) dg = 1.f;
      float v = acc[r][ch] * rsqrtf(dg) + bias[ch];
      acc[r][ch] = v > 0.f ? v : 0.f;
    }
    __syncthreads();
    // fused gemm2: out[n][c2] = (sum_c B[n][c] * W2[c][c2]) * rsqrt(deg_out[n])
    int w = t >> 6, lane = t & 63;
    int rg = lane >> 4, cg = lane & 15;
    int r0 = w * 16 + rg * 4;
    int c0 = cg * 4;
    float oacc[4][4];
#pragma unroll
    for (int i = 0; i < 4; i++)
#pragma unroll
      for (int j = 0; j < 4; j++) oacc[i][j] = 0.f;
#pragma unroll 4
    for (int d = 0; d < 64; d++) {
      float4 b = *(const float4*)&W2[d * HIDDEN + c0];  // global, L1-resident
      float a0 = acc[r0 + 0][d], a1 = acc[r0 + 1][d];
      float a2 = acc[r0 + 2][d], a3 = acc[r0 + 3][d];
      oacc[0][0] += a0 * b.x; oacc[0][1] += a0 * b.y; oacc[0][2] += a0 * b.z; oacc[0][3] += a0 * b.w;
      oacc[1][0] += a1 * b.x; oacc[1][1] += a1 * b.y; oacc[1][2] += a1 * b.z; oacc[1][3] += a1 * b.w;
      oacc[2][0] += a2 * b.x; oacc[2][1] += a2 * b.y; oacc[2][2] += a2 * b.z; oacc[2][3] += a2 * b.w;
      oacc[3][0] += a3 * b.x; oacc[3][1] += a3 * b.y; oacc[3][2] += a3 * b.z; oacc[3][3] += a3 * b.w;
    }
#pragma unroll
    for (int i = 0; i < 4; i++) {
      int node = node0 + r0 + i;
      if (node >= N_NODES) continue;
      float dg = (float)deg_out[node];
      if (dg < 1.f) dg = 1.f;
      float sc = rsqrtf(dg);
      __half2 p0 = __floats2half2_rn(oacc[i][0] * sc, oacc[i][1] * sc);
      __half2 p1 = __floats2half2_rn(oacc[i][2] * sc, oacc[i][3] * sc);
      union { __half2 h2[2]; float2 f2; } u;
      u.h2[0] = p0; u.h2[1] = p1;
      *(float2*)&out[(size_t)node * HIDDEN + c0] = u.f2;
    }
  } else {
    // MODE 2: fused mean-pool partial sums. v = relu(scale+bias); accumulate per graph.
    if (t < 64) {
      int node = node0 + t;
      ngs[t] = (node < N_NODES) ? node_graph[node] : -1;
    }
    __syncthreads();
    int ch = t & 63, q = t >> 6;
    bool uniform = (ngs[0] >= 0) && (ngs[0] == ngs[63]);
    if (uniform) {
      // whole block in one graph: block-reduce then 64 atomics total
      float a = 0.f;
      for (int r = q * 16; r < q * 16 + 16; r++) {
        float dg = (float)deg_in[node0 + r];
        if (dg < 1.f) dg = 1.f;
        float v = acc[r][ch] * rsqrtf(dg) + bias[ch];
        a += (v > 0.f ? v : 0.f);
      }
      psum[q][ch] = a;
      __syncthreads();
      if (t < 64) {
        float s4 = psum[0][t] + psum[1][t] + psum[2][t] + psum[3][t];
        atomicAdd(&sums[ngs[0] * HIDDEN + t], s4);
      }
    } else {
      // boundary block: run-flush per 16-row quarter
      int curg = -1; float a = 0.f;
      for (int r = q * 16; r < q * 16 + 16; r++) {
        int g = ngs[r];
        if (g != curg) {
          if (curg >= 0) atomicAdd(&sums[curg * HIDDEN + ch], a);
          curg = g; a = 0.f;
        }
        if (g >= 0) {
          float dg = (float)deg_in[node0 + r];
          if (dg < 1.f) dg = 1.f;
          float v = acc[r][ch] * rsqrtf(dg) + bias[ch];
          a += (v > 0.f ? v : 0.f);
        }
      }
      if (curg >= 0) atomicAdd(&sums[curg * HIDDEN + ch], a);
    }
  }
}

// ---------------- final: h_graph = sums/counts; mu/logvar = h_graph @ Wmu/Wlv + b ----------------
__global__ __launch_bounds__(256) void final_k(const float* __restrict__ sums,
                                               const float* __restrict__ counts,
                                               const float* __restrict__ Wmu,
                                               const float* __restrict__ bmu,
                                               const float* __restrict__ Wlv,
                                               const float* __restrict__ blv,
                                               float* __restrict__ out) {
  __shared__ float hg[N_GRAPHS][HIDDEN];
  __shared__ float wmu[HIDDEN][LATENT];
  __shared__ float wlv[HIDDEN][LATENT];
  int t = threadIdx.x;
  for (int i = t; i < N_GRAPHS * HIDDEN; i += 256) {
    int g = i / HIDDEN;
    float c = counts[g];
    if (c < 1.f) c = 1.f;
    hg[g][i % HIDDEN] = sums[i] / c;
  }
  for (int i = t; i < HIDDEN * LATENT; i += 256) {
    wmu[i / LATENT][i % LATENT] = Wmu[i];
    wlv[i / LATENT][i % LATENT] = Wlv[i];
  }
  __syncthreads();
  for (int i = t; i < N_GRAPHS * LATENT; i += 256) {
    int g = i / LATENT, j = i % LATENT;
    float mu = bmu[j], lv = blv[j];
#pragma unroll
    for (int k = 0; k < HIDDEN; k++) {
      float v = hg[g][k];
      mu += v * wmu[k][j];
      lv += v * wlv[k][j];
    }
    out[i] = mu;
    out[N_GRAPHS * LATENT + i] = lv;
  }
}

extern "C" void kernel_launch(void* const* d_in, const int* in_sizes, int n_in,
                              void* d_out, int out_size, void* d_ws, size_t ws_size,
                              hipStream_t stream) {
  const float* x = (const float*)d_in[0];
  // d_in[1] = edge_feat: provably unused for (mu, logvar)
  const int* src = (const int*)d_in[2];
  const int* dst = (const int*)d_in[3];
  const int* node_graph = (const int*)d_in[4];
  const float* W1 = (const float*)d_in[5];
  const float* b1 = (const float*)d_in[6];
  const float* W2 = (const float*)d_in[7];
  const float* b2 = (const float*)d_in[8];
  // d_in[9] = We, d_in[10] = be: unused
  const float* Wmu = (const float*)d_in[11];
  const float* bmu = (const float*)d_in[12];
  const float* Wlv = (const float*)d_in[13];
  const float* blv = (const float*)d_in[14];
  float* out = (float*)d_out;

  char* ws = (char*)d_ws;
  // zeroed control block [0, 20992)
  int* bc_src   = (int*)(ws + 0);        // 1024
  int* bc_dst   = (int*)(ws + 1024);     // 1024
  int* cur_src  = (int*)(ws + 2048);     // 1024
  int* cur_dst  = (int*)(ws + 3072);     // 1024
  float* cnts   = (float*)(ws + 4096);   // 512
  float* sums   = (float*)(ws + 4608);   // 16384 -> 20992
  // non-zeroed control
  int* bbase_src = (int*)(ws + 21504);   // 1028 (pad)
  int* bbase_dst = (int*)(ws + 22784);   // 1028 (pad)
  int* tbl_src   = (int*)(ws + 24576);   // 262144 -> 286720
  int* tbl_dst   = (int*)(ws + 286720);  // 262144 -> 548864
  // big arrays
  int* deg_out = (int*)(ws + 548864);    // 400128 -> 948992
  int* deg_in  = (int*)(ws + 948992);    // 400128 -> 1349120
  int* seg     = (int*)(ws + 1349120);   // 401412 pad -> 1750656
  int* eblk    = (int*)(ws + 1750656);   // 12800000 -> 14550656
  int* sortedS = (int*)(ws + 14550656);  // 12800000 -> 27350656 (dead after degout)
  int* sortedE = (int*)(ws + 27350656);  // 12800000 -> 40150656 (dead after fine_sort)
  __half* A1   = (__half*)(ws + 14550656); // alias of sortedS (layer1 gemm out)
  __half* A2   = (__half*)(ws + 27350656); // alias of sortedE (fused agg1+gemm2 out)

  zero_k<<<(20992 / 16 + 255) / 256, 256, 0, stream>>>((int4*)ws, 20992 / 16);

  hist_c_k<<<SC_BLOCKS, 256, 0, stream>>>((const int4*)src, (const int4*)dst,
                                          bc_src, bc_dst, tbl_src, tbl_dst);
  scan_c_k<<<1, 256, 0, stream>>>(bc_src, bc_dst, bbase_src, bbase_dst);
  scatter_c_k<<<SC_BLOCKS, 256, 0, stream>>>((const int4*)src, (const int4*)dst,
                                             bbase_src, bbase_dst, tbl_src, tbl_dst,
                                             cur_src, cur_dst, sortedS, sortedE);
  fine_sort_k<<<NBC_USED, 256, 0, stream>>>(sortedE, bbase_dst, deg_in, seg, eblk);
  degout_c_k<<<NBC_USED, 256, 0, stream>>>(sortedS, bbase_src, deg_out);
  counts_k<<<(N_NODES + 1023) / 1024, 256, 0, stream>>>(node_graph, cnts);

  const int GEMM_BLKS = (N_NODES + 63) / 64;  // 1563

  // layer 1 GEMM: A1 = fp16((x @ W1) * deg_out^-1/2)
  gemm_tile_k<IN_DIM, float, __half><<<GEMM_BLKS, 256, 0, stream>>>(x, W1, deg_out, A1);
  // fused agg1 + gemm2: A2 = fp16( (relu(agg(A1)*deg_in^-1/2 + b1) @ W2) * deg_out^-1/2 )
  agg_seg_k<1><<<NBLK_AGG, 256, 0, stream>>>(A1, eblk, seg, deg_in, b1, W2, deg_out,
                                             nullptr, nullptr, A2);
  // fused agg2 + mean-pool: sums += per-graph sums of relu(agg(A2)*deg_in^-1/2 + b2)
  agg_seg_k<2><<<NBLK_AGG, 256, 0, stream>>>(A2, eblk, seg, deg_in, b2, nullptr, nullptr,
                                             node_graph, sums, nullptr);

  final_k<<<1, 256, 0, stream>>>(sums, cnts, Wmu, bmu, Wlv, blv, out);
}